// Round 3
// baseline (108.935 us; speedup 1.0000x reference)
//
#include <hip/hip_runtime.h>

#define LLRMAX 19.3f
#define BSZ 512
#define KOUT 960

// boxplus exactly as reference: clip both args, log(1+e^(x+y)) - log(e^x+e^y).
// boxp(0,y) == 0 exactly -- used to fold zero-R terms branchlessly.
__device__ __forceinline__ float boxp(float x, float y) {
    x = fminf(fmaxf(x, -LLRMAX), LLRMAX);   // v_med3
    y = fminf(fmaxf(y, -LLRMAX), LLRMAX);
    float ex = __expf(x);
    float ey = __expf(y);
    return __logf(1.0f + ex * ey) - __logf(ex + ey);
}

// Layout: position p = j*512 + tid, j = 0,1; 8 waves per block, one block per
// batch item. Stage pair distance 2^s:
//   s=0..5 : lane xor within wave  -> __shfl_xor
//   s=6,7,8: tid^64/128/256        -> LDS exchange (stride-1, conflict-free)
//   s=9    : j^1                   -> intra-lane, free
// R sparsity (msg_r_in zero off the frozen set + boxp(0,y)==0):
//   r[1..6]: p<64   r[7]: p<128   r[8]: p<256   r[9]: p<512   r[10] unused.
// Forward single-chain identity for s>=6 (r_s[b]==0 there):
//   r_{s+1}[p] = boxp(r_s[p & (2^s-1)], L_{s+1}[p ^ 2^s])
// so after ONE barrier every thread computes r7->r8->r9 privately (3 boxp),
// and holds exactly the r values its backward b-side lanes need.
__global__ __launch_bounds__(512, 4) void polar_bp(const float* __restrict__ in,
                                                   float* __restrict__ out) {
    __shared__ float xbA[1024];   // bwd exchange buffer A (stages 8, 6)
    __shared__ float xbB[1024];   // bwd exchange buffer B (stage 7)
    __shared__ float sL7[128];    // L[7] support (p<128), prev-iter values
    __shared__ float sL8[256];    // L[8] support (p<256)
    __shared__ float sL9[512];    // L[9] support (p<512)
    __shared__ float sR6[64];     // r[6] support (p<64)

    const int tid = threadIdx.x;
    const int batch = blockIdx.x;

    // llr_ch = -in
    const float* inb = in + (size_t)batch * 1024;
    float llr0 = -inb[tid];
    float llr1 = -inb[512 + tid];

    float Ls[7];                  // Ls[1..6]: L[s][tid] snapshots, wave0 lanes
    float Rs[6];                  // Rs[1..5]: r[s][tid], wave0 lanes
#pragma unroll
    for (int s = 0; s < 7; ++s) Ls[s] = 0.f;
#pragma unroll
    for (int s = 0; s < 6; ++s) Rs[s] = 0.f;

    // zero-init L supports for iteration 0 (visible after first barrier)
    if (tid < 128) sL7[tid] = 0.f;
    if (tid < 256) sL8[tid] = 0.f;
    sL9[tid] = 0.f;

    float Lc0 = 0.f, Lc1 = 0.f;

#pragma unroll 1
    for (int it = 0; it < 10; ++it) {
        // ---- forward: wave0 chain r[1..6] via shuffles (registers only) ----
        if (tid < 64) {
            float r = LLRMAX;                      // r[0] on frozen set
#pragma unroll
            for (int s = 0; s <= 5; ++s) {
                float lp = __shfl_xor(Ls[s + 1], 1 << s, 64);
                float rp = __shfl_xor(r, 1 << s, 64);
                bool isB = (tid >> s) & 1;
                float x = isB ? rp : r;            // a: boxp(r, lp+rp); b: boxp(rp, lp)+r
                float y = isB ? lp : lp + rp;
                float c = boxp(x, y);
                r = isB ? c + r : c;
                if (s <= 4) Rs[s + 1] = r;         // keep r[1..5] for backward
            }
            sR6[tid] = r;
        }
        __syncthreads();                           // B1 (the only forward barrier)

        // ---- forward: private r7->r8->r9 chain (single-chain identity) ----
        float r6c = sR6[tid & 63];
        float r7c = boxp(r6c, sL7[(tid & 127) ^ 64]);
        float r8c = boxp(r7c, sL8[(tid & 255) ^ 128]);
        float r9c = boxp(r8c, sL9[tid ^ 256]);

        // ---- backward stage 9 (j^1, intra-lane); l_in = llr, r2 = 0 ----
        float n0 = boxp(llr0, llr1);               // a-side (j=0)
        Lc1 = boxp(r9c, llr0) + llr1;              // b-side (j=1)
        Lc0 = n0;
        float Ls9r = n0;                           // new L[9] support

        // ---- backward stage 8 (tid^256) ----
        xbA[tid] = Lc0;
        xbA[512 + tid] = Lc1;
        __syncthreads();                           // B2
        {
            float p0 = xbA[tid ^ 256];
            float p1 = xbA[512 + (tid ^ 256)];
            bool isB = tid >= 256;
            float x0 = isB ? r8c : Lc0;            // b: boxp(r1,l1)+l2; a: boxp(l1,l2)
            float c0 = boxp(x0, p0);
            Lc0 = isB ? c0 + Lc0 : c0;
            float x1 = isB ? 0.f : Lc1;            // j=1: r=0 -> b-side no-op
            float c1 = boxp(x1, p1);
            Lc1 = isB ? c1 + Lc1 : c1;
            sL9[tid] = Ls9r;                       // post-B2: old reads done pre-B2
            if (!isB) sL8[tid] = Lc0;              // new L[8] support
        }

        // ---- backward stage 7 (tid^128) ----
        xbB[tid] = Lc0;
        xbB[512 + tid] = Lc1;
        __syncthreads();                           // B3
        {
            float p0 = xbB[tid ^ 128];
            float p1 = xbB[512 + (tid ^ 128)];
            bool isB = (tid >> 7) & 1;
            float r1 = (isB && tid < 256) ? r7c : 0.f;  // r[7] support p<128
            float x0 = isB ? r1 : Lc0;
            float c0 = boxp(x0, p0);
            Lc0 = isB ? c0 + Lc0 : c0;
            float x1 = isB ? 0.f : Lc1;
            float c1 = boxp(x1, p1);
            Lc1 = isB ? c1 + Lc1 : c1;
            if (tid < 128) sL7[tid] = Lc0;         // new L[7] support (post-B3)
        }

        // ---- backward stage 6 (tid^64) ----
        xbA[tid] = Lc0;                            // reuse A: stage-8 reads ended pre-B3
        xbA[512 + tid] = Lc1;
        __syncthreads();                           // B4
        {
            float p0 = xbA[tid ^ 64];
            float p1 = xbA[512 + (tid ^ 64)];
            bool isB = (tid >> 6) & 1;
            float r1 = (isB && tid < 128) ? r6c : 0.f;  // r[6] support p<64
            float x0 = isB ? r1 : Lc0;
            float c0 = boxp(x0, p0);
            Lc0 = isB ? c0 + Lc0 : c0;
            float x1 = isB ? 0.f : Lc1;
            float c1 = boxp(x1, p1);
            Lc1 = isB ? c1 + Lc1 : c1;
            Ls[6] = Lc0;                           // wave0 lanes: L[6] support
        }

        // ---- backward stages 5..1 (intra-wave shuffles) ----
#pragma unroll
        for (int s = 5; s >= 1; --s) {
            const int m = 1 << s;
            float rv = (tid < 64) ? Rs[s] : 0.f;   // r[s] support p<64 (wave0, j=0)
            float rp = __shfl_xor(rv, m, 64);
            float lp0 = __shfl_xor(Lc0, m, 64);
            float lp1 = __shfl_xor(Lc1, m, 64);
            bool isB = (tid >> s) & 1;
            float x0 = isB ? rp : Lc0;             // a: boxp(l1, lp+rp); b: boxp(rp,lp)+l2
            float y0 = isB ? lp0 : lp0 + rp;
            float c0 = boxp(x0, y0);
            Lc0 = isB ? c0 + Lc0 : c0;
            float x1 = isB ? 0.f : Lc1;            // j=1: r = 0 everywhere
            float c1 = boxp(x1, lp1);
            Lc1 = isB ? c1 + Lc1 : c1;
            Ls[s] = Lc0;
        }
        // stage 0 deferred: l_msgs[0] only feeds the output.
    }

    // ---- final stage 0 -> output. Info positions p>=64 have r1=r2=0:
    // even p: -boxp(l1,l2); odd p: -l2.
    {
        float lp0 = __shfl_xor(Lc0, 1, 64);
        float lp1 = __shfl_xor(Lc1, 1, 64);
        bool odd = tid & 1;
        float o0 = odd ? -Lc0 : -boxp(Lc0, lp0);
        float o1 = odd ? -Lc1 : -boxp(Lc1, lp1);
        const size_t ob = (size_t)batch * KOUT;
        if (tid >= 64) out[ob + tid - 64] = o0;    // p in [64,512)
        out[ob + 448 + tid] = o1;                  // p in [512,1024)
    }
}

extern "C" void kernel_launch(void* const* d_in, const int* in_sizes, int n_in,
                              void* d_out, int out_size, void* d_ws, size_t ws_size,
                              hipStream_t stream) {
    const float* in = (const float*)d_in[0];
    float* out = (float*)d_out;
    polar_bp<<<BSZ, 512, 0, stream>>>(in, out);
}

// Round 4
// 73.266 us; speedup vs baseline: 1.4868x; 1.4868x over previous
//
#include <hip/hip_runtime.h>

#define BSZ 512
#define KOUT 960
// e^{+19.3}, e^{-19.3}: exp-domain images of the reference's LLR clip.
#define EMAX 2.4092698e8f
#define EMIN 4.1506346e-9f

// Exponential-domain boxplus. Log-domain: clip both args to +-19.3, then
// log(1+e^(x+y)) - log(e^x+e^y). With E=e^v this is exactly
// (1 + Ex*Ey)/(Ex+Ey) with Ex,Ey clamped to [EMIN,EMAX]. v_rcp_f32 is ~1 ulp.
// boxpE(1,Ey) == 1 to 1 ulp (num,den round identically) -> zero-R no-op.
__device__ __forceinline__ float boxpE(float ex, float ey) {
    ex = fminf(fmaxf(ex, EMIN), EMAX);
    ey = fminf(fmaxf(ey, EMIN), EMAX);
    float num = __builtin_fmaf(ex, ey, 1.0f);
    float den = ex + ey;
    return num * __builtin_amdgcn_rcpf(den);
}

// Layout: position p = j*512 + tid, j = 0,1; 8 waves/block, 1 batch item/block.
//   s=0..5 : lane xor  -> __shfl_xor      s=6,7,8: tid^64/128/256 -> LDS
//   s=9    : j^1       -> intra-lane, free
// All messages stored as E = e^v. Log-domain 0 -> 1.0f, LLRMAX -> EMAX,
// v+w -> E*F. R sparsity and the single-chain forward identity
//   r_{s+1}[p] = boxp(r_s[p & (2^s-1)], L_{s+1}[p ^ 2^s])   (s >= 6)
// are unchanged from the verified log-domain kernel.
__global__ __launch_bounds__(512, 4) void polar_bp(const float* __restrict__ in,
                                                   float* __restrict__ out) {
    __shared__ float xbA[1024];   // bwd exchange buffer A (stages 8, 6)
    __shared__ float xbB[1024];   // bwd exchange buffer B (stage 7)
    __shared__ float sL7[128];    // E(L[7]) support (p<128)
    __shared__ float sL8[256];    // E(L[8]) support (p<256)
    __shared__ float sL9[512];    // E(L[9]) support (p<512)
    __shared__ float sR6[64];     // E(r[6]) support (p<64)

    const int tid = threadIdx.x;
    const int batch = blockIdx.x;

    // llr_ch = -in  ->  E = e^{-in}
    const float* inb = in + (size_t)batch * 1024;
    float llr0 = __expf(-inb[tid]);
    float llr1 = __expf(-inb[512 + tid]);

    float Ls[7];                  // E(L[s])[tid] snapshots, wave0 lanes
    float Rs[6];                  // E(r[s])[tid], wave0 lanes
#pragma unroll
    for (int s = 0; s < 7; ++s) Ls[s] = 1.f;
#pragma unroll
    for (int s = 0; s < 6; ++s) Rs[s] = 1.f;

    if (tid < 128) sL7[tid] = 1.f;
    if (tid < 256) sL8[tid] = 1.f;
    sL9[tid] = 1.f;

    float Lc0 = 1.f, Lc1 = 1.f;

#pragma unroll 1
    for (int it = 0; it < 10; ++it) {
        // ---- forward: wave0 chain r[1..6] via shuffles ----
        if (tid < 64) {
            float r = EMAX;                        // r[0] = LLRMAX on frozen set
#pragma unroll
            for (int s = 0; s <= 5; ++s) {
                float lp = __shfl_xor(Ls[s + 1], 1 << s, 64);
                float rp = __shfl_xor(r, 1 << s, 64);
                bool isB = (tid >> s) & 1;
                float x = isB ? rp : r;            // a: boxp(r, lp*rp); b: boxp(rp,lp)*r
                float y = isB ? lp : lp * rp;
                float c = boxpE(x, y);
                r = isB ? c * r : c;
                if (s <= 4) Rs[s + 1] = r;
            }
            sR6[tid] = r;
        }
        __syncthreads();                           // B1 (only forward barrier)

        // ---- forward: private r7->r8->r9 chain ----
        float r6c = sR6[tid & 63];
        float r7c = boxpE(r6c, sL7[(tid & 127) ^ 64]);
        float r8c = boxpE(r7c, sL8[(tid & 255) ^ 128]);
        float r9c = boxpE(r8c, sL9[tid ^ 256]);

        // ---- backward stage 9 (j^1, intra-lane) ----
        float n0 = boxpE(llr0, llr1);              // a-side (j=0)
        Lc1 = boxpE(r9c, llr0) * llr1;             // b-side (j=1)
        Lc0 = n0;
        float Ls9r = n0;

        // ---- backward stage 8 (tid^256) ----
        xbA[tid] = Lc0;
        xbA[512 + tid] = Lc1;
        __syncthreads();                           // B2
        {
            float p0 = xbA[tid ^ 256];
            float p1 = xbA[512 + (tid ^ 256)];
            bool isB = tid >= 256;
            float x0 = isB ? r8c : Lc0;
            float c0 = boxpE(x0, p0);
            Lc0 = isB ? c0 * Lc0 : c0;
            float x1 = isB ? 1.f : Lc1;            // j=1: r=0 -> no-op via boxpE(1,.)
            float c1 = boxpE(x1, p1);
            Lc1 = isB ? c1 * Lc1 : c1;
            sL9[tid] = Ls9r;
            if (!isB) sL8[tid] = Lc0;
        }

        // ---- backward stage 7 (tid^128) ----
        xbB[tid] = Lc0;
        xbB[512 + tid] = Lc1;
        __syncthreads();                           // B3
        {
            float p0 = xbB[tid ^ 128];
            float p1 = xbB[512 + (tid ^ 128)];
            bool isB = (tid >> 7) & 1;
            float r1 = (isB && tid < 256) ? r7c : 1.f;
            float x0 = isB ? r1 : Lc0;
            float c0 = boxpE(x0, p0);
            Lc0 = isB ? c0 * Lc0 : c0;
            float x1 = isB ? 1.f : Lc1;
            float c1 = boxpE(x1, p1);
            Lc1 = isB ? c1 * Lc1 : c1;
            if (tid < 128) sL7[tid] = Lc0;
        }

        // ---- backward stage 6 (tid^64) ----
        xbA[tid] = Lc0;
        xbA[512 + tid] = Lc1;
        __syncthreads();                           // B4
        {
            float p0 = xbA[tid ^ 64];
            float p1 = xbA[512 + (tid ^ 64)];
            bool isB = (tid >> 6) & 1;
            float r1 = (isB && tid < 128) ? r6c : 1.f;
            float x0 = isB ? r1 : Lc0;
            float c0 = boxpE(x0, p0);
            Lc0 = isB ? c0 * Lc0 : c0;
            float x1 = isB ? 1.f : Lc1;
            float c1 = boxpE(x1, p1);
            Lc1 = isB ? c1 * Lc1 : c1;
            Ls[6] = Lc0;
        }

        // ---- backward stages 5..1 (intra-wave shuffles) ----
#pragma unroll
        for (int s = 5; s >= 1; --s) {
            const int m = 1 << s;
            float rp = 1.f;
            if (tid < 64) rp = __shfl_xor(Rs[s], m, 64);  // wave-uniform branch
            float lp0 = __shfl_xor(Lc0, m, 64);
            float lp1 = __shfl_xor(Lc1, m, 64);
            bool isB = (tid >> s) & 1;
            float x0 = isB ? rp : Lc0;
            float y0 = isB ? lp0 : lp0 * rp;
            float c0 = boxpE(x0, y0);
            Lc0 = isB ? c0 * Lc0 : c0;
            float x1 = isB ? 1.f : Lc1;
            float c1 = boxpE(x1, lp1);
            Lc1 = isB ? c1 * Lc1 : c1;
            Ls[s] = Lc0;
        }
        // stage 0 deferred: l_msgs[0] only feeds the output.
    }

    // ---- final stage 0 -> output. Info positions p>=64 have r1=r2=0:
    // even p: -boxp(l1,l2); odd p: -l2.  Back to log domain with one v_log.
    {
        float lp0 = __shfl_xor(Lc0, 1, 64);
        float lp1 = __shfl_xor(Lc1, 1, 64);
        bool odd = tid & 1;
        float e0 = odd ? Lc0 : boxpE(Lc0, lp0);
        float e1 = odd ? Lc1 : boxpE(Lc1, lp1);
        float o0 = -__logf(e0);
        float o1 = -__logf(e1);
        const size_t ob = (size_t)batch * KOUT;
        if (tid >= 64) out[ob + tid - 64] = o0;    // p in [64,512)
        out[ob + 448 + tid] = o1;                  // p in [512,1024)
    }
}

extern "C" void kernel_launch(void* const* d_in, const int* in_sizes, int n_in,
                              void* d_out, int out_size, void* d_ws, size_t ws_size,
                              hipStream_t stream) {
    const float* in = (const float*)d_in[0];
    float* out = (float*)d_out;
    polar_bp<<<BSZ, 512, 0, stream>>>(in, out);
}

// Round 5
// 62.007 us; speedup vs baseline: 1.7568x; 1.1816x over previous
//
#include <hip/hip_runtime.h>

#define BSZ 512
#define KOUT 960
// e^{+19.3}, e^{-19.3}: exp-domain images of the reference's LLR clip.
#define EMAX 2.4092698e8f
#define EMIN 4.1506346e-9f

// Exp-domain boxplus: (1 + Ex*Ey)/(Ex+Ey), args clamped to the clip range.
__device__ __forceinline__ float boxpE(float ex, float ey) {
    ex = fminf(fmaxf(ex, EMIN), EMAX);
    ey = fminf(fmaxf(ey, EMIN), EMAX);
    float num = __builtin_fmaf(ex, ey, 1.0f);
    return num * __builtin_amdgcn_rcpf(ex + ey);
}
// Args provably within [EMIN, EMAX] (boxpE-output closure) -> the reference
// clip is the identity -> clamps elided.
__device__ __forceinline__ float boxpE_nc(float ex, float ey) {
    float num = __builtin_fmaf(ex, ey, 1.0f);
    return num * __builtin_amdgcn_rcpf(ex + ey);
}

// Position p = j*512 + tid, j=0,1. Stage distance 2^s: s<=5 lane-xor (shfl),
// s=6,7,8 tid^64/128/256 (LDS), s=9 j^1 (intra-lane).
// R sparsity: supp r[1..6]=[0,64), r[7]=[0,128), r[8]=[0,256), r[9]=[0,512).
// KEY: backward restarts from llr each iteration and a-side r-terms are 0 on
// the support region, so the supports L[9][<512], L[8][<256], L[7][<128],
// L[6][<64] are ITERATION-INVARIANT (functions of llr only) -> prologue.
// Per-iteration work reduces to wave0's 64-lane recurrence:
//   fwd r[1..6] (6 boxp, shfl) + bwd L[5..1] (5 boxp, shfl), no barriers.
// Iteration 9 runs the full (R4-verified) pipeline for b-sides + output.
__global__ __launch_bounds__(512, 4) void polar_bp(const float* __restrict__ in,
                                                   float* __restrict__ out) {
    __shared__ float xbA[1024];   // exchange A (prologue s8; final s8, s6)
    __shared__ float xbB[1024];   // exchange B (prologue s7; final s7)
    __shared__ float xbC[128];    // prologue s6 exchange (wave1 -> wave0)
    __shared__ float sL7[128];    // invariant L[7] support
    __shared__ float sL8[256];    // invariant L[8] support
    __shared__ float sL9[512];    // invariant L[9] support
    __shared__ float sR6[64];     // final-iteration r[6]

    const int tid = threadIdx.x;
    const float* inb = in + (size_t)blockIdx.x * 1024;
    float llr0 = __expf(-inb[tid]);
    float llr1 = __expf(-inb[512 + tid]);

    // ---- prologue: iteration-invariant a-side backward chain (r-free) ----
    float n0 = boxpE(llr0, llr1);            // L[9][p], p<512 (every iter)
    sL9[tid] = n0;
    xbA[tid] = n0;
    float Li8 = 0.f, Li7 = 0.f, Li6 = 0.f;
    __syncthreads();                         // P1
    if (tid < 256) {
        Li8 = boxpE_nc(n0, xbA[tid ^ 256]);  // L[8][p], p<256
        sL8[tid] = Li8;
        xbB[tid] = Li8;
    }
    __syncthreads();                         // P2
    if (tid < 128) {
        Li7 = boxpE_nc(Li8, xbB[tid ^ 128]); // L[7][p], p<128
        sL7[tid] = Li7;
        xbC[tid] = Li7;
    }
    __syncthreads();                         // P3
    if (tid < 64) Li6 = boxpE_nc(Li7, xbC[tid + 64]);  // L[6][p], p<64

    // ---- wave0 recurrence: iters 0..8 full, iter 9 forward only ----
    float Rs[6];                             // r[1..5] at wave0 lanes
    if (tid < 64) {
        float Ls[7];                         // L[1..6] support snapshots
#pragma unroll
        for (int s = 0; s < 7; ++s) Ls[s] = 1.f;   // msg_l0 = zeros
#pragma unroll 1
        for (int it = 0; it < 10; ++it) {
            // forward chain r[1]..r[6]
            float r = EMAX;                  // r[0] = LLRMAX on frozen set
#pragma unroll
            for (int s = 0; s <= 5; ++s) {
                float lp = __shfl_xor(Ls[s + 1], 1 << s, 64);
                float rp = __shfl_xor(r, 1 << s, 64);
                bool isB = (tid >> s) & 1;
                float x = isB ? rp : r;      // a: boxp(r, lp*rp); b: boxp(rp,lp)*r
                float y = isB ? lp : lp * rp;
                float c = boxpE(x, y);
                r = isB ? c * r : c;
                if (s <= 4) Rs[s + 1] = r;
            }
            if (it == 9) { sR6[tid] = r; break; }   // final fwd feeds full pass
            // backward stages 5..1 from invariant L[6]
            float Lc = Li6;
#pragma unroll
            for (int s = 5; s >= 1; --s) {
                const int m = 1 << s;
                float rp = __shfl_xor(Rs[s], m, 64);
                float lp = __shfl_xor(Lc, m, 64);
                bool isB = (tid >> s) & 1;
                float x = isB ? rp : Lc;
                float y = isB ? lp : lp * rp;
                float c = boxpE(x, y);
                Lc = isB ? c * Lc : c;
                Ls[s] = Lc;
            }
            Ls[6] = Li6;
        }
    }
    __syncthreads();                         // B1

    // ---- final iteration: full pipeline (verified R4 structure) ----
    // r-chain: r_{s+1}[p] = boxp(r_s[p & (2^s-1)], L_{s+1}[p ^ 2^s]), s>=6
    float r6c = sR6[tid & 63];
    float r7c = boxpE(r6c, sL7[(tid & 127) ^ 64]);
    float r8c = boxpE(r7c, sL8[(tid & 255) ^ 128]);
    float r9c = boxpE(r8c, sL9[tid ^ 256]);

    // stage 9 (j^1, intra-lane)
    float Lc0 = n0;
    float Lc1 = boxpE(r9c, llr0) * llr1;

    // stage 8 (tid^256)
    xbA[tid] = Lc0;
    xbA[512 + tid] = Lc1;
    __syncthreads();                         // B2
    {
        float p0 = xbA[tid ^ 256];
        float p1 = xbA[512 + (tid ^ 256)];
        bool isB = tid >= 256;
        float x0 = isB ? r8c : Lc0;
        float c0 = boxpE(x0, p0);
        Lc0 = isB ? c0 * Lc0 : c0;
        float x1 = isB ? 1.f : Lc1;          // j=1: r=0 -> exact no-op
        float c1 = boxpE(x1, p1);
        Lc1 = isB ? c1 * Lc1 : c1;
    }

    // stage 7 (tid^128)
    xbB[tid] = Lc0;
    xbB[512 + tid] = Lc1;
    __syncthreads();                         // B3
    {
        float p0 = xbB[tid ^ 128];
        float p1 = xbB[512 + (tid ^ 128)];
        bool isB = (tid >> 7) & 1;
        float r1 = (isB && tid < 256) ? r7c : 1.f;
        float x0 = isB ? r1 : Lc0;
        float c0 = boxpE(x0, p0);
        Lc0 = isB ? c0 * Lc0 : c0;
        float x1 = isB ? 1.f : Lc1;
        float c1 = boxpE(x1, p1);
        Lc1 = isB ? c1 * Lc1 : c1;
    }

    // stage 6 (tid^64) — reuse xbA (its stage-8 reads completed before B3)
    xbA[tid] = Lc0;
    xbA[512 + tid] = Lc1;
    __syncthreads();                         // B4
    {
        float p0 = xbA[tid ^ 64];
        float p1 = xbA[512 + (tid ^ 64)];
        bool isB = (tid >> 6) & 1;
        float r1 = (isB && tid < 128) ? r6c : 1.f;
        float x0 = isB ? r1 : Lc0;
        float c0 = boxpE(x0, p0);
        Lc0 = isB ? c0 * Lc0 : c0;
        float x1 = isB ? 1.f : Lc1;
        float c1 = boxpE(x1, p1);
        Lc1 = isB ? c1 * Lc1 : c1;
    }

    // stages 5..1 (intra-wave shuffles); Rs valid on wave0 (final-iter values)
#pragma unroll
    for (int s = 5; s >= 1; --s) {
        const int m = 1 << s;
        float rp = 1.f;
        if (tid < 64) rp = __shfl_xor(Rs[s], m, 64);
        float lp0 = __shfl_xor(Lc0, m, 64);
        float lp1 = __shfl_xor(Lc1, m, 64);
        bool isB = (tid >> s) & 1;
        float x0 = isB ? rp : Lc0;
        float y0 = isB ? lp0 : lp0 * rp;
        float c0 = boxpE(x0, y0);
        Lc0 = isB ? c0 * Lc0 : c0;
        float x1 = isB ? 1.f : Lc1;
        float c1 = boxpE(x1, lp1);
        Lc1 = isB ? c1 * Lc1 : c1;
    }

    // ---- final stage 0 -> output. p>=64 have r1=r2=0:
    // even p: -boxp(l1,l2); odd p: -l2. One v_log back to log domain.
    {
        float lp0 = __shfl_xor(Lc0, 1, 64);
        float lp1 = __shfl_xor(Lc1, 1, 64);
        bool odd = tid & 1;
        float e0 = odd ? Lc0 : boxpE(Lc0, lp0);
        float e1 = odd ? Lc1 : boxpE(Lc1, lp1);
        float o0 = -__logf(e0);
        float o1 = -__logf(e1);
        const size_t ob = (size_t)blockIdx.x * KOUT;
        if (tid >= 64) out[ob + tid - 64] = o0;    // p in [64,512)
        out[ob + 448 + tid] = o1;                  // p in [512,1024)
    }
}

extern "C" void kernel_launch(void* const* d_in, const int* in_sizes, int n_in,
                              void* d_out, int out_size, void* d_ws, size_t ws_size,
                              hipStream_t stream) {
    const float* in = (const float*)d_in[0];
    float* out = (float*)d_out;
    polar_bp<<<BSZ, 512, 0, stream>>>(in, out);
}